// Round 7
// baseline (186.568 us; speedup 1.0000x reference)
//
#include <hip/hip_runtime.h>
#include <hip/hip_bf16.h>

#define IMG   512
#define TW    32            // tile cols
#define TH    128           // tile rows (4 wave-quadrants of 32)
#define WS    11
#define NP    96
#define NSLOT 256
#define JROWS 138           // computed H rows = TH + 10
#define JPAD  144           // rows JROWS..143 zeroed (read range ends at 143)
#define KSTR  152           // u16 k-stride per col (16B-aligned, bank-spread)
#define PLANE (32*KSTR)     // u16 per signal plane (4864)

typedef __attribute__((ext_vector_type(8)))  short bfrag8;
typedef __attribute__((ext_vector_type(16))) float facc16;

#define GAUSS_W { \
    0.00102837990674f, 0.00759883148699f, 0.03600079242909f, \
    0.10936069869137f, 0.21300538108707f, 0.26601190869814f, \
    0.21300538108707f, 0.10936069869137f, 0.03600079242909f, \
    0.00759883148699f, 0.00102837990674f }

static __device__ __forceinline__ ushort f2bf(float x) {
    __hip_bfloat16 h = __float2bfloat16(x);
    return __builtin_bit_cast(ushort, h);
}

// A-operand (Gaussian band) fragments: G[i][k] = W[k-i], 32x32x16 A-layout:
// lane l holds A[l&31][8*(l>>5)+e]. hi at gw[0..1535], lo at gw[1536..3071].
__global__ void build_g(ushort* __restrict__ gw) {
    constexpr float W[WS] = GAUSS_W;
    const int lane = threadIdx.x;          // 64 threads
    const int row  = lane & 31;
    const int kg   = (lane >> 5) * 8;
    for (int s = 0; s < 3; ++s) {
        for (int e = 0; e < 8; ++e) {
            const int k = 16 * s + kg + e;
            const int d = k - row;
            float wv = 0.f;
            #pragma unroll
            for (int q = 0; q < WS; ++q) if (d == q) wv = W[q];
            const float hi = __bfloat162float(__float2bfloat16(wv));
            const float lo = wv - hi;
            gw[(s * 64 + lane) * 8 + e]        = f2bf(hi);
            gw[1536 + (s * 64 + lane) * 8 + e] = f2bf(lo);
        }
    }
}

__global__ __launch_bounds__(256, 3) void ssim_main(const float* __restrict__ img1,
                                                    const float* __restrict__ img2,
                                                    const ushort* __restrict__ gw,
                                                    double* __restrict__ acc) {
    constexpr float W[WS] = GAUSS_W;
    // H transposed: HT[s*PLANE + col*KSTR + k] (u16 idx, XOR-swizzled bits 3-4)
    __shared__ ushort HT[5 * PLANE];   // 48,640 B -> 3 blocks/CU

    const int tid = threadIdx.x;
    const int bx = blockIdx.x;   // 0..15 (cols)
    const int by = blockIdx.y;   // 0..3  (rows)
    const float* p1 = img1 + (size_t)blockIdx.z * (IMG * IMG);
    const float* p2 = img2 + (size_t)blockIdx.z * (IMG * IMG);

    // zero pad rows JROWS..JPAD-1 (read by quadrant-3 B-frags; G taps are 0 there,
    // but 0*garbage could be NaN)
    for (int i = tid; i < 5 * 32 * (JPAD - JROWS); i += 256) {
        const int s   = i / (32 * (JPAD - JROWS));
        const int rem = i - s * 32 * (JPAD - JROWS);
        const int col = rem / (JPAD - JROWS);
        const int k   = JROWS + rem - col * (JPAD - JROWS);
        HT[(size_t)s * PLANE + ((col * KSTR + k) ^ (((col >> 3) & 3) << 3))] = 0;
    }

    // A-operand fragments (issue early; L2-broadcast)
    const bfrag8* gfrag = (const bfrag8*)gw;
    const int lane = tid & 63;
    const bfrag8 ghi0 = gfrag[lane], ghi1 = gfrag[64 + lane], ghi2 = gfrag[128 + lane];
    const bfrag8 glo0 = gfrag[192 + lane], glo1 = gfrag[256 + lane], glo2 = gfrag[320 + lane];

    // ---------- Phase 1: horizontal conv, write bf16 transposed -------------
    const bool xInterior = (bx > 0) & (bx < 15);
    for (int u = tid; u < JROWS * 4; u += 256) {    // 552 units
        const int r  = u >> 2;          // H row (k index), 0..137
        const int ch = u & 3;           // 8-wide col chunk
        const int gy = by * TH + r - 5;

        float a1[8], a2[8], a11[8], a22[8], a12[8];
        #pragma unroll
        for (int o = 0; o < 8; ++o) { a1[o]=0.f; a2[o]=0.f; a11[o]=0.f; a22[o]=0.f; a12[o]=0.f; }

        if ((unsigned)gy < IMG) {
            const float* r1 = p1 + (size_t)gy * IMG;
            const float* r2 = p2 + (size_t)gy * IMG;
            float v1[24], v2[24];
            if (xInterior) {
                #pragma unroll
                for (int j = 0; j < 6; ++j) {
                    const int gx = bx * TW + ch * 8 - 8 + 4 * j;
                    const float4 A = *(const float4*)(r1 + gx);
                    const float4 B = *(const float4*)(r2 + gx);
                    v1[4*j+0]=A.x; v1[4*j+1]=A.y; v1[4*j+2]=A.z; v1[4*j+3]=A.w;
                    v2[4*j+0]=B.x; v2[4*j+1]=B.y; v2[4*j+2]=B.z; v2[4*j+3]=B.w;
                }
            } else {
                #pragma unroll
                for (int j = 0; j < 6; ++j) {
                    const int gx = bx * TW + ch * 8 - 8 + 4 * j;
                    float4 A = make_float4(0.f,0.f,0.f,0.f), B = A;
                    if ((unsigned)gx < IMG) {
                        A = *(const float4*)(r1 + gx);
                        B = *(const float4*)(r2 + gx);
                    }
                    v1[4*j+0]=A.x; v1[4*j+1]=A.y; v1[4*j+2]=A.z; v1[4*j+3]=A.w;
                    v2[4*j+0]=B.x; v2[4*j+1]=B.y; v2[4*j+2]=B.z; v2[4*j+3]=B.w;
                }
            }
            #pragma unroll
            for (int i = 3; i <= 20; ++i) {
                const float x1 = v1[i], x2 = v2[i];
                const float q11 = x1*x1, q22 = x2*x2, q12 = x1*x2;
                #pragma unroll
                for (int o = 0; o < 8; ++o) {
                    const int t = i - 3 - o;
                    if (t >= 0 && t < WS) {
                        a1[o]  += W[t]*x1;  a2[o]  += W[t]*x2;
                        a11[o] += W[t]*q11; a22[o] += W[t]*q22; a12[o] += W[t]*q12;
                    }
                }
            }
        }

        // transposed scatter: col = ch*8+e, key (col>>3)&3 == ch (constant)
        #pragma unroll
        for (int e = 0; e < 8; ++e) {
            const int idx = (((ch * 8 + e) * KSTR + r) ^ (ch << 3));
            HT[idx]             = f2bf(a1[e]);
            HT[idx +   PLANE]   = f2bf(a2[e]);
            HT[idx + 2*PLANE]   = f2bf(a11[e]);
            HT[idx + 3*PLANE]   = f2bf(a22[e]);
            HT[idx + 4*PLANE]   = f2bf(a12[e]);
        }
    }
    __syncthreads();

    // ---------- Phase 2: vertical conv via MFMA, one quadrant per wave ------
    const int w   = tid >> 6;        // 0..3: output rows w*32..w*32+31
    const int col = lane & 31;
    const int hh  = lane >> 5;
    const int key = ((col >> 3) & 3) << 3;

    facc16 accs[5];
    #pragma unroll
    for (int s = 0; s < 5; ++s) {
        facc16 a = {};
        #define KSTEP(T, GHI, GLO) { \
            const int kb = w * 32 + 16 * T + hh * 8; \
            const bfrag8 bv = *(const bfrag8*)&HT[s * PLANE + ((col * KSTR + kb) ^ key)]; \
            a = __builtin_amdgcn_mfma_f32_32x32x16_bf16(GHI, bv, a, 0, 0, 0); \
            a = __builtin_amdgcn_mfma_f32_32x32x16_bf16(GLO, bv, a, 0, 0, 0); }
        KSTEP(0, ghi0, glo0)
        KSTEP(1, ghi1, glo1)
        KSTEP(2, ghi2, glo2)
        #undef KSTEP
        accs[s] = a;
    }

    // ---------- Epilogue: SSIM per pixel (layout-invariant sum) -------------
    const float C1 = 0.01f*0.01f, C2 = 0.03f*0.03f;
    float lsum = 0.f;
    #pragma unroll
    for (int r = 0; r < 16; ++r) {
        const float mu1 = accs[0][r], mu2 = accs[1][r];
        const float m11 = accs[2][r], m22 = accs[3][r], m12 = accs[4][r];
        const float mu1s = mu1*mu1, mu2s = mu2*mu2, mu12 = mu1*mu2;
        const float s11 = m11 - mu1s;
        const float s22 = m22 - mu2s;
        const float s12 = m12 - mu12;
        const float num = (2.f*mu12 + C1) * (2.f*s12 + C2);
        const float den = (mu1s + mu2s + C1) * (s11 + s22 + C2);
        lsum += num * __builtin_amdgcn_rcpf(den);
    }

    #pragma unroll
    for (int d = 32; d >= 1; d >>= 1)
        lsum += __shfl_down(lsum, d, 64);
    if (lane == 0) {
        const int bid = (blockIdx.z * gridDim.y + blockIdx.y) * gridDim.x + blockIdx.x;
        atomicAdd(&acc[(bid * 4 + w) & (NSLOT - 1)], (double)lsum);
    }
}

__global__ void ssim_final(const double* __restrict__ acc, float* __restrict__ out) {
    const int l = threadIdx.x;   // 64 threads
    double s = acc[l] + acc[l + 64] + acc[l + 128] + acc[l + 192];
    #pragma unroll
    for (int d = 32; d >= 1; d >>= 1)
        s += __shfl_down(s, d, 64);
    if (l == 0)
        out[0] = 1.0f - (float)(s / (double)((size_t)NP * IMG * IMG));
}

extern "C" void kernel_launch(void* const* d_in, const int* in_sizes, int n_in,
                              void* d_out, int out_size, void* d_ws, size_t ws_size,
                              hipStream_t stream) {
    const float* img1 = (const float*)d_in[0];
    const float* img2 = (const float*)d_in[1];
    float* out = (float*)d_out;
    double* acc = (double*)d_ws;
    ushort* gw = (ushort*)((char*)d_ws + NSLOT * sizeof(double));

    hipMemsetAsync(d_ws, 0, NSLOT * sizeof(double), stream);
    build_g<<<1, 64, 0, stream>>>(gw);

    dim3 grid(IMG / TW, IMG / TH, NP);
    ssim_main<<<grid, dim3(256), 0, stream>>>(img1, img2, gw, acc);
    ssim_final<<<1, dim3(64), 0, stream>>>(acc, out);
}

// Round 9
// 125.781 us; speedup vs baseline: 1.4833x; 1.4833x over previous
//
#include <hip/hip_runtime.h>
#include <hip/hip_bf16.h>

#define IMG   512
#define TW    64
#define TH    32
#define WS    11
#define NP    96
#define NSLOT 256
#define PR    21            // pair-rows (42 h-conv rows as bf16 pairs)
#define PLANE (PR*64)       // u32 words per signal plane (1344)

static __device__ __forceinline__ ushort f2bf(float x) {
    __hip_bfloat16 h = __float2bfloat16(x);
    return __builtin_bit_cast(ushort, h);
}
static __device__ __forceinline__ uint pkbf(float ev, float od) {
    return (uint)f2bf(ev) | ((uint)f2bf(od) << 16);
}
static __device__ __forceinline__ float bflo(uint v) {   // even row
    return __builtin_bit_cast(float, v << 16);
}
static __device__ __forceinline__ float bfhi(uint v) {   // odd row
    return __builtin_bit_cast(float, v & 0xffff0000u);
}

__global__ __launch_bounds__(256, 4) void ssim_main(const float* __restrict__ img1,
                                                    const float* __restrict__ img2,
                                                    double* __restrict__ acc) {
    constexpr float W[WS] = {
        0.00102837990674f, 0.00759883148699f, 0.03600079242909f,
        0.10936069869137f, 0.21300538108707f, 0.26601190869814f,
        0.21300538108707f, 0.10936069869137f, 0.03600079242909f,
        0.00759883148699f, 0.00102837990674f };

    // 5 signal planes, bf16 row-pairs: HP[(s*PR+p)*64 + col] = bf16(H[2p][col]) | bf16(H[2p+1][col])<<16
    __shared__ uint HP[5 * PLANE];   // 26,880 B -> 6 blocks/CU

    const int tid = threadIdx.x;
    const int bx = blockIdx.x;   // 0..7
    const int by = blockIdx.y;   // 0..15
    const float* p1 = img1 + (size_t)blockIdx.z * (IMG * IMG);
    const float* p2 = img2 + (size_t)blockIdx.z * (IMG * IMG);

    // ---------- Phase 1: horizontal conv, 2 rows x 4 cols per unit ----------
    for (int u = tid; u < PR * 16; u += 256) {        // 336 units
        const int pr = u >> 4;        // pair-row 0..20
        const int cg = u & 15;        // 4-col group

        float A[5][2][4];
        #pragma unroll
        for (int s = 0; s < 5; ++s)
            #pragma unroll
            for (int rw = 0; rw < 2; ++rw)
                #pragma unroll
                for (int o = 0; o < 4; ++o) A[s][rw][o] = 0.f;

        #pragma unroll
        for (int rw = 0; rw < 2; ++rw) {
            const int gy = by * TH + 2 * pr + rw - 5;
            const bool rowOK = (unsigned)gy < IMG;
            const float* r1 = p1 + (size_t)gy * IMG;
            const float* r2 = p2 + (size_t)gy * IMG;
            #pragma unroll
            for (int j = 0; j < 5; ++j) {
                const int gx = bx * TW + cg * 4 - 8 + 4 * j;
                float4 X = make_float4(0.f,0.f,0.f,0.f), Y = X;
                if (rowOK && (unsigned)gx < IMG) {
                    X = *(const float4*)(r1 + gx);
                    Y = *(const float4*)(r2 + gx);
                }
                const float e1[4] = {X.x,X.y,X.z,X.w};
                const float e2[4] = {Y.x,Y.y,Y.z,Y.w};
                #pragma unroll
                for (int e = 0; e < 4; ++e) {
                    const int i = 4*j + e;            // input px rel (c0-8); taps live 3..16
                    if (i < 3 || i > 16) continue;
                    const float x1 = e1[e], x2 = e2[e];
                    const float q11 = x1*x1, q22 = x2*x2, q12 = x1*x2;
                    #pragma unroll
                    for (int o = 0; o < 4; ++o) {
                        const int t = i - 3 - o;
                        if (t >= 0 && t < WS) {
                            A[0][rw][o] += W[t]*x1;  A[1][rw][o] += W[t]*x2;
                            A[2][rw][o] += W[t]*q11; A[3][rw][o] += W[t]*q22;
                            A[4][rw][o] += W[t]*q12;
                        }
                    }
                }
            }
        }

        #pragma unroll
        for (int s = 0; s < 5; ++s) {
            const uint4 pv = make_uint4(pkbf(A[s][0][0], A[s][1][0]),
                                        pkbf(A[s][0][1], A[s][1][1]),
                                        pkbf(A[s][0][2], A[s][1][2]),
                                        pkbf(A[s][0][3], A[s][1][3]));
            *(uint4*)&HP[(s * PR + pr) * 64 + cg * 4] = pv;
        }
    }
    __syncthreads();

    // ---------- Phase 2: vertical conv, 2 rows x 4 cols per thread ----------
    const int q0 = tid >> 4;     // out row-pair (rows 2q0, 2q0+1)
    const int cg = tid & 15;     // 4-col group

    float m[5][2][4];
    #pragma unroll
    for (int s = 0; s < 5; ++s)
        #pragma unroll
        for (int pth = 0; pth < 2; ++pth)
            #pragma unroll
            for (int c = 0; c < 4; ++c) m[s][pth][c] = 0.f;

    #pragma unroll
    for (int s = 0; s < 5; ++s) {
        #pragma unroll
        for (int j = 0; j <= 5; ++j) {
            const uint4 v = *(const uint4*)&HP[(s * PR + q0 + j) * 64 + cg * 4];
            const uint vv[4] = {v.x, v.y, v.z, v.w};
            #pragma unroll
            for (int c = 0; c < 4; ++c) {
                const float lo = bflo(vv[c]);   // k = 2(q0+j)
                const float hi = bfhi(vv[c]);   // k = 2(q0+j)+1
                // even out-row (r = 2q0): t = 2j (lo), 2j+1 (hi)
                if (2*j < WS)     m[s][0][c] += W[2*j] * lo;
                if (2*j+1 < WS)   m[s][0][c] += W[2*j+1] * hi;
                // odd out-row (r = 2q0+1): t = 2j-1 (lo), 2j (hi)
                if (2*j-1 >= 0)   m[s][1][c] += W[2*j-1] * lo;
                if (2*j < WS)     m[s][1][c] += W[2*j] * hi;
            }
        }
    }

    // ---------- Epilogue: SSIM for 8 px ------------------------------------
    const float C1 = 0.01f*0.01f, C2 = 0.03f*0.03f;
    float lsum = 0.f;
    #pragma unroll
    for (int pth = 0; pth < 2; ++pth) {
        #pragma unroll
        for (int c = 0; c < 4; ++c) {
            const float mu1 = m[0][pth][c], mu2 = m[1][pth][c];
            const float mu1s = mu1*mu1, mu2s = mu2*mu2, mu12 = mu1*mu2;
            const float s11 = m[2][pth][c] - mu1s;
            const float s22 = m[3][pth][c] - mu2s;
            const float s12 = m[4][pth][c] - mu12;
            const float num = (2.f*mu12 + C1) * (2.f*s12 + C2);
            const float den = (mu1s + mu2s + C1) * (s11 + s22 + C2);
            lsum += num * __builtin_amdgcn_rcpf(den);
        }
    }

    // wave reduce + block reduce + spread atomic
    #pragma unroll
    for (int d = 32; d >= 1; d >>= 1)
        lsum += __shfl_down(lsum, d, 64);
    __shared__ float wsum[4];
    if ((tid & 63) == 0) wsum[tid >> 6] = lsum;
    __syncthreads();
    if (tid == 0) {
        const float t = wsum[0] + wsum[1] + wsum[2] + wsum[3];
        const int bid = (blockIdx.z * gridDim.y + blockIdx.y) * gridDim.x + blockIdx.x;
        atomicAdd(&acc[bid & (NSLOT - 1)], (double)t);
    }
}

__global__ void ssim_final(const double* __restrict__ acc, float* __restrict__ out) {
    const int l = threadIdx.x;   // 64 threads
    double s = acc[l] + acc[l + 64] + acc[l + 128] + acc[l + 192];
    #pragma unroll
    for (int d = 32; d >= 1; d >>= 1)
        s += __shfl_down(s, d, 64);
    if (l == 0)
        out[0] = 1.0f - (float)(s / (double)((size_t)NP * IMG * IMG));
}

extern "C" void kernel_launch(void* const* d_in, const int* in_sizes, int n_in,
                              void* d_out, int out_size, void* d_ws, size_t ws_size,
                              hipStream_t stream) {
    const float* img1 = (const float*)d_in[0];
    const float* img2 = (const float*)d_in[1];
    float* out = (float*)d_out;
    double* acc = (double*)d_ws;

    hipMemsetAsync(d_ws, 0, NSLOT * sizeof(double), stream);

    dim3 grid(IMG / TW, IMG / TH, NP);
    ssim_main<<<grid, dim3(256), 0, stream>>>(img1, img2, acc);
    ssim_final<<<1, dim3(64), 0, stream>>>(acc, out);
}